// Round 1
// baseline (1186.291 us; speedup 1.0000x reference)
//
#include <hip/hip_runtime.h>

#define NN 16
#define KC 16
#define HEADS 4
#define HC 64
#define F1 256
#define HS 260   // padded LDS row stride (floats) for 256-wide buffers

struct SMem {
  float hA[NN][HS];     // 16640 B
  float hB[NN][HS];     // 16640 B
  float wch[KC][F1];    // 16384 B
  float asd[2][NN][HEADS];  // a_src, a_dst scores
  float ew[NN][HEADS][6];   // normalized edge weights per dst
  float o64[NN][68];        // GAT2 per-node output (mean over heads)
  float grb[64];
  float y1b[128];
  float z1b[128];
  float red[8];
};

// adjacency (incoming srcs per dst: self + grid neighbors), 4x4 grid
__device__ __constant__ int ADJ_DEG[16] = {3,4,4,3, 4,5,5,4, 4,5,5,4, 3,4,4,3};
__device__ __constant__ int ADJ_SRC[16][5] = {
  {0,1,4,0,0},   {1,0,2,5,0},   {2,1,3,6,0},   {3,2,7,0,0},
  {4,5,0,8,0},   {5,4,6,1,9},   {6,5,7,2,10},  {7,6,3,11,0},
  {8,9,4,12,0},  {9,8,10,5,13}, {10,9,11,6,14},{11,10,7,15,0},
  {12,13,8,0,0}, {13,12,14,9,0},{14,13,15,10,0},{15,14,11,0,0}
};

// x[16 x FIN] @ W[FIN x 256] -> xQ[16 x 256], W staged through LDS in KC-row chunks
template<int FIN>
__device__ __forceinline__ void gemm_tile(const float (*hP)[HS], float (*xQ)[HS],
                                          float (*wch)[F1], const float* __restrict__ W,
                                          int t) {
  const int n = t >> 4, l16 = t & 15;
  float acc[16];
#pragma unroll
  for (int i = 0; i < 16; ++i) acc[i] = 0.f;
  for (int k0 = 0; k0 < FIN; k0 += KC) {
    __syncthreads();  // previous chunk consumed (also orders hP writes on first iter)
    const float4* wg = reinterpret_cast<const float4*>(W + (size_t)k0 * F1);
    float4* wl = reinterpret_cast<float4*>(&wch[0][0]);
#pragma unroll
    for (int r = 0; r < 4; ++r) wl[r * 256 + t] = wg[r * 256 + t];
    __syncthreads();
#pragma unroll
    for (int kk = 0; kk < KC; ++kk) {
      const float hv = hP[n][k0 + kk];
      const float4* wrow = reinterpret_cast<const float4*>(&wch[kk][0]);
#pragma unroll
      for (int j = 0; j < 4; ++j) {
        const float4 wv = wrow[l16 + 16 * j];
        acc[4*j+0] = fmaf(hv, wv.x, acc[4*j+0]);
        acc[4*j+1] = fmaf(hv, wv.y, acc[4*j+1]);
        acc[4*j+2] = fmaf(hv, wv.z, acc[4*j+2]);
        acc[4*j+3] = fmaf(hv, wv.w, acc[4*j+3]);
      }
    }
  }
#pragma unroll
  for (int j = 0; j < 4; ++j) {
    float4 v;
    v.x = acc[4*j+0]; v.y = acc[4*j+1]; v.z = acc[4*j+2]; v.w = acc[4*j+3];
    *reinterpret_cast<float4*>(&xQ[n][4 * l16 + 64 * j]) = v;
  }
}

__device__ __forceinline__ void attention_stage(const float (*xQ)[HS], SMem& sm,
                                                const float* __restrict__ as_g,
                                                const float* __restrict__ ad_g, int t) {
  __syncthreads();  // xQ complete
  if (t < 64) {
    const int n = t >> 2, h = t & 3;
    const float4* xr = reinterpret_cast<const float4*>(&xQ[n][h * HC]);
    const float4* a1 = reinterpret_cast<const float4*>(as_g + h * HC);
    const float4* a2 = reinterpret_cast<const float4*>(ad_g + h * HC);
    float s1 = 0.f, s2 = 0.f;
#pragma unroll
    for (int q = 0; q < 16; ++q) {
      const float4 xv = xr[q];
      const float4 u = a1[q];
      const float4 v = a2[q];
      s1 += xv.x*u.x + xv.y*u.y + xv.z*u.z + xv.w*u.w;
      s2 += xv.x*v.x + xv.y*v.y + xv.z*v.z + xv.w*v.w;
    }
    sm.asd[0][n][h] = s1;
    sm.asd[1][n][h] = s2;
  }
  __syncthreads();
  if (t < 64) {
    const int d = t >> 2, h = t & 3;
    const int deg = ADJ_DEG[d];
    const float advl = sm.asd[1][d][h];
    float al[5];
    float m = -1e30f;
#pragma unroll
    for (int k = 0; k < 5; ++k) {
      if (k < deg) {
        float v = sm.asd[0][ADJ_SRC[d][k]][h] + advl;
        v = (v > 0.f) ? v : 0.2f * v;       // leaky_relu slope 0.2
        al[k] = v;
        m = fmaxf(m, v);
      }
    }
    float s = 0.f;
#pragma unroll
    for (int k = 0; k < 5; ++k) {
      if (k < deg) { const float e = __expf(al[k] - m); al[k] = e; s += e; }
    }
    const float inv = 1.f / s;
#pragma unroll
    for (int k = 0; k < 5; ++k) {
      if (k < deg) sm.ew[d][h][k] = al[k] * inv;
    }
  }
  __syncthreads();
}

template<bool CONCAT>
__device__ __forceinline__ void aggregate_stage(const float (*xQ)[HS], float (*hOut)[HS],
                                                SMem& sm, const float* __restrict__ bias,
                                                int t) {
  const int d = t >> 4, q = t & 15;
  const int deg = ADJ_DEG[d];
  if (CONCAT) {
#pragma unroll
    for (int j = 0; j < HEADS; ++j) {
      float ax = 0.f, ay = 0.f, az = 0.f, aw = 0.f;
#pragma unroll
      for (int k = 0; k < 5; ++k) {
        if (k < deg) {
          const float w = sm.ew[d][j][k];
          const float4 xv = *reinterpret_cast<const float4*>(&xQ[ADJ_SRC[d][k]][j*HC + 4*q]);
          ax = fmaf(w, xv.x, ax); ay = fmaf(w, xv.y, ay);
          az = fmaf(w, xv.z, az); aw = fmaf(w, xv.w, aw);
        }
      }
      const float4 b4 = *reinterpret_cast<const float4*>(&bias[j*HC + 4*q]);
      float4 o;
      o.x = fmaxf(ax + b4.x, 0.f);   // + bias then relu (relu applied after layers 0/1)
      o.y = fmaxf(ay + b4.y, 0.f);
      o.z = fmaxf(az + b4.z, 0.f);
      o.w = fmaxf(aw + b4.w, 0.f);
      *reinterpret_cast<float4*>(&hOut[d][j*HC + 4*q]) = o;
    }
  } else {
    float ax = 0.f, ay = 0.f, az = 0.f, aw = 0.f;
#pragma unroll
    for (int j = 0; j < HEADS; ++j) {
#pragma unroll
      for (int k = 0; k < 5; ++k) {
        if (k < deg) {
          const float w = sm.ew[d][j][k];
          const float4 xv = *reinterpret_cast<const float4*>(&xQ[ADJ_SRC[d][k]][j*HC + 4*q]);
          ax = fmaf(w, xv.x, ax); ay = fmaf(w, xv.y, ay);
          az = fmaf(w, xv.z, az); aw = fmaf(w, xv.w, aw);
        }
      }
    }
    const float4 b4 = *reinterpret_cast<const float4*>(&bias[4*q]);
    float4 o;
    o.x = fmaf(0.25f, ax, b4.x);   // mean over 4 heads + bias2, no relu
    o.y = fmaf(0.25f, ay, b4.y);
    o.z = fmaf(0.25f, az, b4.z);
    o.w = fmaf(0.25f, aw, b4.w);
    *reinterpret_cast<float4*>(&sm.o64[d][4*q]) = o;
  }
}

extern "C" __global__ void __launch_bounds__(256, 2)
gat_fused(const float* __restrict__ xg,
          const float* __restrict__ w_in, const float* __restrict__ b_in,
          const float* __restrict__ w0, const float* __restrict__ as0,
          const float* __restrict__ ad0, const float* __restrict__ bias0,
          const float* __restrict__ w1, const float* __restrict__ as1,
          const float* __restrict__ ad1, const float* __restrict__ bias1,
          const float* __restrict__ w2, const float* __restrict__ as2,
          const float* __restrict__ ad2, const float* __restrict__ bias2,
          const float* __restrict__ mw1, const float* __restrict__ mb1,
          const float* __restrict__ g1, const float* __restrict__ be1,
          const float* __restrict__ mw2, const float* __restrict__ mb2,
          const float* __restrict__ g2, const float* __restrict__ be2,
          float* __restrict__ out, int nbatch, int Btot)
{
  __shared__ SMem sm;
  const int t = threadIdx.x;
  const int n = t >> 4, l16 = t & 15;
  const int lane = t & 63, wid = t >> 6;

  for (int bb = 0; bb < nbatch; ++bb) {
    const int b = blockIdx.x * nbatch + bb;
    if (b >= Btot) break;                    // uniform across block
    __syncthreads();                         // previous batch fully consumed

    // ---- stage 1: x[b,c,i,j] -> h0[n][c] in hB (n = i*4+j) ----
    sm.hB[t & 15][t >> 4] = xg[(size_t)b * 256 + t];
    __syncthreads();

    // ---- stage 2: h1 = relu(h0 @ w_in + b_in) -> hA[16][64] ----
    {
      float ax = 0.f, ay = 0.f, az = 0.f, aw = 0.f;
#pragma unroll
      for (int c = 0; c < 16; ++c) {
        const float hv = sm.hB[n][c];
        const float4 wv = *reinterpret_cast<const float4*>(&w_in[c * 64 + 4 * l16]);
        ax = fmaf(hv, wv.x, ax); ay = fmaf(hv, wv.y, ay);
        az = fmaf(hv, wv.z, az); aw = fmaf(hv, wv.w, aw);
      }
      const float4 b4 = *reinterpret_cast<const float4*>(&b_in[4 * l16]);
      float4 o;
      o.x = fmaxf(ax + b4.x, 0.f); o.y = fmaxf(ay + b4.y, 0.f);
      o.z = fmaxf(az + b4.z, 0.f); o.w = fmaxf(aw + b4.w, 0.f);
      *reinterpret_cast<float4*>(&sm.hA[n][4 * l16]) = o;
    }

    // ---- GAT layer 0 (64 -> 4x64 concat, relu) ----
    gemm_tile<64>(sm.hA, sm.hB, sm.wch, w0, t);
    attention_stage(sm.hB, sm, as0, ad0, t);
    aggregate_stage<true>(sm.hB, sm.hA, sm, bias0, t);

    // ---- GAT layer 1 (256 -> 4x64 concat, relu) ----
    gemm_tile<256>(sm.hA, sm.hB, sm.wch, w1, t);
    attention_stage(sm.hB, sm, as1, ad1, t);
    aggregate_stage<true>(sm.hB, sm.hA, sm, bias1, t);

    // ---- GAT layer 2 (256 -> 64, mean over heads) ----
    gemm_tile<256>(sm.hA, sm.hB, sm.wch, w2, t);
    attention_stage(sm.hB, sm, as2, ad2, t);
    aggregate_stage<false>(sm.hB, sm.hA, sm, bias2, t);
    __syncthreads();

    // ---- global mean pool over 16 nodes ----
    if (t < 64) {
      float s = 0.f;
#pragma unroll
      for (int d2 = 0; d2 < 16; ++d2) s += sm.o64[d2][t];
      sm.grb[t] = s * (1.f / 16.f);
    }
    __syncthreads();

    // ---- MLP1: [64] -> [128] ----
    if (t < 128) {
      float s = mb1[t];
#pragma unroll 8
      for (int c = 0; c < 64; ++c) s = fmaf(sm.grb[c], mw1[c * 128 + t], s);
      sm.y1b[t] = s;
    }
    __syncthreads();

    // ---- LN(128) + relu ----
    if (t < 128) {
      const float v = sm.y1b[t];
      float s = v, s2 = v * v;
#pragma unroll
      for (int off = 32; off >= 1; off >>= 1) {
        s  += __shfl_xor(s, off);
        s2 += __shfl_xor(s2, off);
      }
      if (lane == 0) { sm.red[wid * 2] = s; sm.red[wid * 2 + 1] = s2; }
    }
    __syncthreads();
    {
      const float mu  = (sm.red[0] + sm.red[2]) * (1.f / 128.f);
      const float msq = (sm.red[1] + sm.red[3]) * (1.f / 128.f);
      const float rstd = rsqrtf(msq - mu * mu + 1e-5f);
      if (t < 128) {
        const float z = (sm.y1b[t] - mu) * rstd * g1[t] + be1[t];
        sm.z1b[t] = fmaxf(z, 0.f);
      }
    }
    __syncthreads();

    // ---- MLP2: [128] -> [256], LN(256) + relu, store ----
    {
      float s = mb2[t];
#pragma unroll 8
      for (int f = 0; f < 128; ++f) s = fmaf(sm.z1b[f], mw2[f * 256 + t], s);
      float su = s, sq = s * s;
#pragma unroll
      for (int off = 32; off >= 1; off >>= 1) {
        su += __shfl_xor(su, off);
        sq += __shfl_xor(sq, off);
      }
      __syncthreads();   // LN1 red reads done
      if (lane == 0) { sm.red[wid * 2] = su; sm.red[wid * 2 + 1] = sq; }
      __syncthreads();
      const float mu  = (sm.red[0] + sm.red[2] + sm.red[4] + sm.red[6]) * (1.f / 256.f);
      const float msq = (sm.red[1] + sm.red[3] + sm.red[5] + sm.red[7]) * (1.f / 256.f);
      const float z = (s - mu) * rsqrtf(msq - mu * mu + 1e-5f) * g2[t] + be2[t];
      out[(size_t)b * 256 + t] = fmaxf(z, 0.f);
    }
  }
}

extern "C" void kernel_launch(void* const* d_in, const int* in_sizes, int n_in,
                              void* d_out, int out_size, void* d_ws, size_t ws_size,
                              hipStream_t stream) {
  const float* xg   = (const float*)d_in[0];
  const float* w_in = (const float*)d_in[1];
  const float* b_in = (const float*)d_in[2];
  const float* w0   = (const float*)d_in[3];
  const float* as0  = (const float*)d_in[4];
  const float* ad0  = (const float*)d_in[5];
  const float* bi0  = (const float*)d_in[6];
  const float* w1   = (const float*)d_in[7];
  const float* as1  = (const float*)d_in[8];
  const float* ad1  = (const float*)d_in[9];
  const float* bi1  = (const float*)d_in[10];
  const float* w2   = (const float*)d_in[11];
  const float* as2  = (const float*)d_in[12];
  const float* ad2  = (const float*)d_in[13];
  const float* bi2  = (const float*)d_in[14];
  const float* mw1  = (const float*)d_in[15];
  const float* mb1  = (const float*)d_in[16];
  const float* g1   = (const float*)d_in[17];
  const float* be1  = (const float*)d_in[18];
  const float* mw2  = (const float*)d_in[19];
  const float* mb2  = (const float*)d_in[20];
  const float* g2   = (const float*)d_in[21];
  const float* be2  = (const float*)d_in[22];
  float* out = (float*)d_out;

  const int Btot = in_sizes[0] / 256;          // 8192
  const int nblocks = 512;                     // 2 blocks/CU, exactly fills 256 CUs
  const int nbatch = (Btot + nblocks - 1) / nblocks;

  hipLaunchKernelGGL(gat_fused, dim3(nblocks), dim3(256), 0, stream,
                     xg, w_in, b_in, w0, as0, ad0, bi0, w1, as1, ad1, bi1,
                     w2, as2, ad2, bi2, mw1, mb1, g1, be1, mw2, mb2, g2, be2,
                     out, nbatch, Btot);
}

// Round 2
// 324.983 us; speedup vs baseline: 3.6503x; 3.6503x over previous
//
#include <hip/hip_runtime.h>

typedef unsigned short u16;
typedef unsigned int   u32;
typedef __attribute__((ext_vector_type(8))) short bf16x8;
typedef __attribute__((ext_vector_type(4))) float f32x4;

#define GPB 8   // graphs per block; M = 16*GPB = 128 rows

__constant__ int ADJ_DEG[16] = {3,4,4,3, 4,5,5,4, 4,5,5,4, 3,4,4,3};
__constant__ int ADJ_SRC[16][5] = {
  {0,1,4,0,0},   {1,0,2,5,0},   {2,1,3,6,0},   {3,2,7,0,0},
  {4,5,0,8,0},   {5,4,6,1,9},   {6,5,7,2,10},  {7,6,3,11,0},
  {8,9,4,12,0},  {9,8,10,5,13}, {10,9,11,6,14},{11,10,7,15,0},
  {12,13,8,0,0}, {13,12,14,9,0},{14,13,15,10,0},{15,14,11,0,0}
};

struct SMem {
  char hA[128*512];   // bf16 [128 rows][256 cols], XOR-swizzled
  char hB[128*512];   // bf16 [128 rows][256 cols], XOR-swizzled (GEMM output x)
  union {
    char wbuf[16384];                                        // one 32-K W chunk (bf16 frags)
    struct { float h0f[128][20]; float w_in_s[16][64]; } pre;
    struct { float asd[2][128][4]; float ew[8][16][4][5]; } post;
    struct { float z1[8][128]; float grb[8][64]; } mlp;
  } u;
};

__device__ __forceinline__ int swz(int row, int b) { return (row << 9) + (b ^ ((row & 7) << 4)); }
__device__ __forceinline__ u32 f2bf1(float x) {           // RNE float->bf16 bits
  u32 u = __float_as_uint(x);
  return (u + 0x7fffu + ((u >> 16) & 1u)) >> 16;
}
__device__ __forceinline__ u32 pk(float a, float b) { return f2bf1(a) | (f2bf1(b) << 16); }
__device__ __forceinline__ float bflo(u32 u) { return __uint_as_float(u << 16); }
__device__ __forceinline__ float bfhi(u32 u) { return __uint_as_float(u & 0xffff0000u); }
__device__ __forceinline__ void fma4(float4& a, float s, float4 w) {
  a.x = fmaf(s, w.x, a.x); a.y = fmaf(s, w.y, a.y);
  a.z = fmaf(s, w.z, a.z); a.w = fmaf(s, w.w, a.w);
}

// ---- GEMM: hA[128 x 32*KC] (bf16, swizzled) @ Wfrag -> hB (bf16, swizzled) ----
template<int KC>
__device__ __forceinline__ void gemm(SMem& sm, const u16* wfrag, int t) {
  const int lane = t & 63, wid = t >> 6;
  const int wr = wid >> 2, wc = wid & 3;       // wave owns m-tiles 4*wr.., n-tiles 4*wc..
  const uint4* wsrc = (const uint4*)wfrag;
  uint4* wb = (uint4*)sm.u.wbuf;

  f32x4 zero4 = {0.f, 0.f, 0.f, 0.f};
  f32x4 acc[4][4];
#pragma unroll
  for (int i = 0; i < 4; ++i)
#pragma unroll
    for (int j = 0; j < 4; ++j) acc[i][j] = zero4;

  // prologue: stage chunk 0 (caller barrier guarantees wbuf free + hA ready)
  uint4 r0 = wsrc[2*t], r1 = wsrc[2*t + 1];
  wb[2*t] = r0; wb[2*t + 1] = r1;

#pragma unroll
  for (int kc = 0; kc < KC; ++kc) {
    if (kc + 1 < KC) {               // issue next chunk loads early (hide L2 under MFMA)
      r0 = wsrc[(kc+1)*1024 + 2*t];
      r1 = wsrc[(kc+1)*1024 + 2*t + 1];
    }
    __syncthreads();                 // wbuf[kc] ready
    bf16x8 a[4];
#pragma unroll
    for (int i = 0; i < 4; ++i)
      a[i] = *(const bf16x8*)(sm.hA + swz(wr*64 + i*16 + (lane & 15),
                                          kc*64 + 16*(lane >> 4)));
#pragma unroll
    for (int jn = 0; jn < 4; ++jn) {
      bf16x8 b = *(const bf16x8*)(sm.u.wbuf + (((wc*4 + jn)*64 + lane) << 4));
#pragma unroll
      for (int i = 0; i < 4; ++i)
        acc[i][jn] = __builtin_amdgcn_mfma_f32_16x16x32_bf16(a[i], b, acc[i][jn], 0, 0, 0);
    }
    __syncthreads();                 // all reads of wbuf done
    if (kc + 1 < KC) { wb[2*t] = r0; wb[2*t + 1] = r1; }
  }

  // epilogue: acc (fp32) -> hB bf16 swizzled. lane: col = nt*16+(lane&15), rows (lane>>4)*4+reg
#pragma unroll
  for (int i = 0; i < 4; ++i) {
    const int rbase = wr*64 + i*16 + (lane >> 4)*4;
#pragma unroll
    for (int jn = 0; jn < 4; ++jn) {
      const int col = (wc*4 + jn)*16 + (lane & 15);
#pragma unroll
      for (int reg = 0; reg < 4; ++reg)
        *(u16*)(sm.hB + swz(rbase + reg, 2*col)) = (u16)f2bf1(acc[i][jn][reg]);
    }
  }
  __syncthreads();
}

// ---- attention: dots (a_s, a_d) + per-dst softmax over fixed adjacency ----
__device__ __forceinline__ void attention(SMem& sm, const float* __restrict__ as_g,
                                          const float* __restrict__ ad_g, int t) {
  {
    const int g = t >> 6, w = t & 63, n = w >> 2, h = w & 3;
    const int row = (g << 4) + n;
    float s1 = 0.f, s2 = 0.f;
#pragma unroll
    for (int i = 0; i < 8; ++i) {
      const int c0 = h*64 + 8*i;
      uint4 xv = *(const uint4*)(sm.hB + swz(row, 2*c0));
      float4 u0 = *(const float4*)(as_g + c0);
      float4 u1 = *(const float4*)(as_g + c0 + 4);
      float4 v0 = *(const float4*)(ad_g + c0);
      float4 v1 = *(const float4*)(ad_g + c0 + 4);
      float x0 = bflo(xv.x), x1 = bfhi(xv.x), x2 = bflo(xv.y), x3 = bfhi(xv.y);
      float x4 = bflo(xv.z), x5 = bfhi(xv.z), x6 = bflo(xv.w), x7 = bfhi(xv.w);
      s1 += x0*u0.x + x1*u0.y + x2*u0.z + x3*u0.w + x4*u1.x + x5*u1.y + x6*u1.z + x7*u1.w;
      s2 += x0*v0.x + x1*v0.y + x2*v0.z + x3*v0.w + x4*v1.x + x5*v1.y + x6*v1.z + x7*v1.w;
    }
    sm.u.post.asd[0][row][h] = s1;
    sm.u.post.asd[1][row][h] = s2;
  }
  __syncthreads();
  {
    const int g = t >> 6, w = t & 63, d = w >> 2, h = w & 3;
    const int deg = ADJ_DEG[d];
    const float advl = sm.u.post.asd[1][(g << 4) + d][h];
    float al[5]; float m = -1e30f;
#pragma unroll
    for (int k = 0; k < 5; ++k) {
      if (k < deg) {
        float v = sm.u.post.asd[0][(g << 4) + ADJ_SRC[d][k]][h] + advl;
        v = (v > 0.f) ? v : 0.2f * v;
        al[k] = v; m = fmaxf(m, v);
      }
    }
    float s = 0.f;
#pragma unroll
    for (int k = 0; k < 5; ++k)
      if (k < deg) { float e = __expf(al[k] - m); al[k] = e; s += e; }
    const float inv = 1.f / s;
#pragma unroll
    for (int k = 0; k < 5; ++k)
      if (k < deg) sm.u.post.ew[g][d][h][k] = al[k] * inv;
  }
  __syncthreads();
}

// ---- aggregate: MODE 0 = concat heads + bias + relu -> hA (bf16); MODE 1 = mean heads + bias -> o64 fp32 (hA region) ----
template<int MODE>
__device__ __forceinline__ void aggregate(SMem& sm, const float* __restrict__ bias, int t) {
  const int g = t >> 6, w = t & 63, d = w >> 2, cq = w & 3;
  const int deg = ADJ_DEG[d];
  const int drow = (g << 4) + d;
  float wgt[5]; int srow[5];
#pragma unroll
  for (int k = 0; k < 5; ++k) {
    wgt[k]  = (k < deg) ? sm.u.post.ew[g][d][cq][k] : 0.f;
    srow[k] = (g << 4) + ADJ_SRC[d][k];
  }
  float (*o64)[68] = (float (*)[68])sm.hA;

#pragma unroll
  for (int ch = 0; ch < 8; ++ch) {
    const int c0 = cq*64 + ch*8;
    float a0 = 0.f, a1 = 0.f, a2 = 0.f, a3 = 0.f, a4 = 0.f, a5 = 0.f, a6 = 0.f, a7 = 0.f;
#pragma unroll
    for (int k = 0; k < 5; ++k) {
      uint4 xv = *(const uint4*)(sm.hB + swz(srow[k], 2*c0));
      const float wk = wgt[k];
      a0 = fmaf(wk, bflo(xv.x), a0); a1 = fmaf(wk, bfhi(xv.x), a1);
      a2 = fmaf(wk, bflo(xv.y), a2); a3 = fmaf(wk, bfhi(xv.y), a3);
      a4 = fmaf(wk, bflo(xv.z), a4); a5 = fmaf(wk, bfhi(xv.z), a5);
      a6 = fmaf(wk, bflo(xv.w), a6); a7 = fmaf(wk, bfhi(xv.w), a7);
    }
    if (MODE == 0) {
      float4 b0 = *(const float4*)(bias + c0);
      float4 b1 = *(const float4*)(bias + c0 + 4);
      float o0 = fmaxf(a0 + b0.x, 0.f), o1 = fmaxf(a1 + b0.y, 0.f);
      float o2 = fmaxf(a2 + b0.z, 0.f), o3 = fmaxf(a3 + b0.w, 0.f);
      float o4 = fmaxf(a4 + b1.x, 0.f), o5 = fmaxf(a5 + b1.y, 0.f);
      float o6 = fmaxf(a6 + b1.z, 0.f), o7 = fmaxf(a7 + b1.w, 0.f);
      uint4 uo;
      uo.x = pk(o0, o1); uo.y = pk(o2, o3); uo.z = pk(o4, o5); uo.w = pk(o6, o7);
      *(uint4*)(sm.hA + swz(drow, 2*c0)) = uo;
    } else {
      // sum over the 4 heads (lanes t, t^1, t^2 share (g,d))
      a0 += __shfl_xor(a0, 1); a0 += __shfl_xor(a0, 2);
      a1 += __shfl_xor(a1, 1); a1 += __shfl_xor(a1, 2);
      a2 += __shfl_xor(a2, 1); a2 += __shfl_xor(a2, 2);
      a3 += __shfl_xor(a3, 1); a3 += __shfl_xor(a3, 2);
      a4 += __shfl_xor(a4, 1); a4 += __shfl_xor(a4, 2);
      a5 += __shfl_xor(a5, 1); a5 += __shfl_xor(a5, 2);
      a6 += __shfl_xor(a6, 1); a6 += __shfl_xor(a6, 2);
      a7 += __shfl_xor(a7, 1); a7 += __shfl_xor(a7, 2);
      // lane cq writes elements 2cq, 2cq+1 of this 8-chunk (c' = ch*8 + 2cq)
      float e0 = (cq == 0) ? a0 : (cq == 1) ? a2 : (cq == 2) ? a4 : a6;
      float e1 = (cq == 0) ? a1 : (cq == 1) ? a3 : (cq == 2) ? a5 : a7;
      const int cp = ch*8 + 2*cq;
      float2 wv;
      wv.x = fmaf(0.25f, e0, bias[cp]);
      wv.y = fmaf(0.25f, e1, bias[cp + 1]);
      *(float2*)&o64[drow][cp] = wv;
    }
  }
}

extern "C" __global__ void __launch_bounds__(512, 2)
gat_main(const float* __restrict__ xg,
         const float* __restrict__ w_in, const float* __restrict__ b_in,
         const float* __restrict__ as0, const float* __restrict__ ad0, const float* __restrict__ bias0,
         const float* __restrict__ as1, const float* __restrict__ ad1, const float* __restrict__ bias1,
         const float* __restrict__ as2, const float* __restrict__ ad2, const float* __restrict__ bias2,
         const float* __restrict__ mw1, const float* __restrict__ mb1,
         const float* __restrict__ g1, const float* __restrict__ be1,
         const float* __restrict__ mw2, const float* __restrict__ mb2,
         const float* __restrict__ g2, const float* __restrict__ be2,
         const u16* __restrict__ wf0, const u16* __restrict__ wf1, const u16* __restrict__ wf2,
         float* __restrict__ out, int Btot)
{
  __shared__ SMem sm;
  const int t = threadIdx.x;
  const int b0 = blockIdx.x * GPB;
  if (b0 >= Btot) return;

  // ---- load x -> h0f[row][c] (fp32), stage w_in ----
  {
    float4 v = *(const float4*)(xg + (size_t)b0*256 + 4*t);
    const int flat = 4*t, g = flat >> 8, rem = flat & 255;
    const int c = rem >> 4, n0 = rem & 15;
    sm.u.pre.h0f[(g << 4) + n0 + 0][c] = v.x;
    sm.u.pre.h0f[(g << 4) + n0 + 1][c] = v.y;
    sm.u.pre.h0f[(g << 4) + n0 + 2][c] = v.z;
    sm.u.pre.h0f[(g << 4) + n0 + 3][c] = v.w;
  }
  if (t < 256) ((float4*)sm.u.pre.w_in_s)[t] = ((const float4*)w_in)[t];
  __syncthreads();

  // ---- in-proj: h1 = relu(h0 @ w_in + b_in) -> hA[.][0..63] bf16 swizzled ----
  {
    const int r = t >> 2, q = t & 3;   // row, 16-col group
    float hk[16];
    *(float4*)&hk[0]  = *(const float4*)&sm.u.pre.h0f[r][0];
    *(float4*)&hk[4]  = *(const float4*)&sm.u.pre.h0f[r][4];
    *(float4*)&hk[8]  = *(const float4*)&sm.u.pre.h0f[r][8];
    *(float4*)&hk[12] = *(const float4*)&sm.u.pre.h0f[r][12];
    float4 ac0 = *(const float4*)&b_in[16*q + 0];
    float4 ac1 = *(const float4*)&b_in[16*q + 4];
    float4 ac2 = *(const float4*)&b_in[16*q + 8];
    float4 ac3 = *(const float4*)&b_in[16*q + 12];
#pragma unroll
    for (int k = 0; k < 16; ++k) {
      const float hv = hk[k];
      const float* wr_ = &sm.u.pre.w_in_s[k][16*q];
      fma4(ac0, hv, *(const float4*)(wr_ + 0));
      fma4(ac1, hv, *(const float4*)(wr_ + 4));
      fma4(ac2, hv, *(const float4*)(wr_ + 8));
      fma4(ac3, hv, *(const float4*)(wr_ + 12));
    }
    ac0.x = fmaxf(ac0.x, 0.f); ac0.y = fmaxf(ac0.y, 0.f); ac0.z = fmaxf(ac0.z, 0.f); ac0.w = fmaxf(ac0.w, 0.f);
    ac1.x = fmaxf(ac1.x, 0.f); ac1.y = fmaxf(ac1.y, 0.f); ac1.z = fmaxf(ac1.z, 0.f); ac1.w = fmaxf(ac1.w, 0.f);
    ac2.x = fmaxf(ac2.x, 0.f); ac2.y = fmaxf(ac2.y, 0.f); ac2.z = fmaxf(ac2.z, 0.f); ac2.w = fmaxf(ac2.w, 0.f);
    ac3.x = fmaxf(ac3.x, 0.f); ac3.y = fmaxf(ac3.y, 0.f); ac3.z = fmaxf(ac3.z, 0.f); ac3.w = fmaxf(ac3.w, 0.f);
    uint4 u0, u1;
    u0.x = pk(ac0.x, ac0.y); u0.y = pk(ac0.z, ac0.w); u0.z = pk(ac1.x, ac1.y); u0.w = pk(ac1.z, ac1.w);
    u1.x = pk(ac2.x, ac2.y); u1.y = pk(ac2.z, ac2.w); u1.z = pk(ac3.x, ac3.y); u1.w = pk(ac3.z, ac3.w);
    *(uint4*)(sm.hA + swz(r, 32*q))      = u0;
    *(uint4*)(sm.hA + swz(r, 32*q + 16)) = u1;
  }
  __syncthreads();   // hA ready; pre region dead -> wbuf usable

  // ---- GAT layer 0 (K=64) ----
  gemm<2>(sm, wf0, t);
  attention(sm, as0, ad0, t);
  aggregate<0>(sm, bias0, t);
  __syncthreads();

  // ---- GAT layer 1 (K=256) ----
  gemm<8>(sm, wf1, t);
  attention(sm, as1, ad1, t);
  aggregate<0>(sm, bias1, t);
  __syncthreads();

  // ---- GAT layer 2 (K=256, mean heads) ----
  gemm<8>(sm, wf2, t);
  attention(sm, as2, ad2, t);
  aggregate<1>(sm, bias2, t);
  __syncthreads();

  // ---- global mean pool (per graph = per wave) ----
  {
    const int g = t >> 6, l = t & 63;
    float (*o64)[68] = (float (*)[68])sm.hA;
    float s = 0.f;
#pragma unroll
    for (int r = 0; r < 16; ++r) s += o64[(g << 4) + r][l];
    sm.u.mlp.grb[g][l] = s * (1.f / 16.f);
  }
  __syncthreads();

  // ---- MLP1 [64]->[128], LN, relu ----
  {
    const int g = t >> 6, l = t & 63;
    float a0 = mb1[2*l], a1 = mb1[2*l + 1];
#pragma unroll 8
    for (int k = 0; k < 64; ++k) {
      const float gk = sm.u.mlp.grb[g][k];
      float2 wv = *(const float2*)(mw1 + k*128 + 2*l);
      a0 = fmaf(gk, wv.x, a0); a1 = fmaf(gk, wv.y, a1);
    }
    float su = a0 + a1, sq = a0*a0 + a1*a1;
#pragma unroll
    for (int off = 32; off >= 1; off >>= 1) { su += __shfl_xor(su, off); sq += __shfl_xor(sq, off); }
    const float mu = su * (1.f/128.f);
    const float rstd = rsqrtf(sq * (1.f/128.f) - mu*mu + 1e-5f);
    float z0 = fmaxf((a0 - mu)*rstd*g1[2*l]   + be1[2*l],   0.f);
    float z1v = fmaxf((a1 - mu)*rstd*g1[2*l+1] + be1[2*l+1], 0.f);
    float2 zw; zw.x = z0; zw.y = z1v;
    *(float2*)&sm.u.mlp.z1[g][2*l] = zw;
  }
  __syncthreads();

  // ---- MLP2 [128]->[256], LN, relu, store ----
  {
    const int g = t >> 6, l = t & 63;
    float4 c = *(const float4*)&mb2[4*l];
#pragma unroll 8
    for (int k = 0; k < 128; ++k) {
      const float zk = sm.u.mlp.z1[g][k];
      fma4(c, zk, *(const float4*)(mw2 + k*256 + 4*l));
    }
    float su = c.x + c.y + c.z + c.w;
    float sq = c.x*c.x + c.y*c.y + c.z*c.z + c.w*c.w;
#pragma unroll
    for (int off = 32; off >= 1; off >>= 1) { su += __shfl_xor(su, off); sq += __shfl_xor(sq, off); }
    const float mu = su * (1.f/256.f);
    const float rstd = rsqrtf(sq * (1.f/256.f) - mu*mu + 1e-5f);
    float4 gv = *(const float4*)&g2[4*l];
    float4 bv = *(const float4*)&be2[4*l];
    float4 o;
    o.x = fmaxf((c.x - mu)*rstd*gv.x + bv.x, 0.f);
    o.y = fmaxf((c.y - mu)*rstd*gv.y + bv.y, 0.f);
    o.z = fmaxf((c.z - mu)*rstd*gv.z + bv.z, 0.f);
    o.w = fmaxf((c.w - mu)*rstd*gv.w + bv.w, 0.f);
    *(float4*)(out + (size_t)(b0 + g)*256 + 4*l) = o;
  }
}

// ---- prepass: w0/w1/w2 fp32 [K][256] -> bf16 MFMA B-fragment layout in d_ws ----
// frag element index: ((kc*16 + nt)*64 + lane)*8 + j  ->  W[kc*32 + (lane>>4)*8 + j][nt*16 + (lane&15)]
__global__ void __launch_bounds__(256)
prep_w(const float* __restrict__ w0, const float* __restrict__ w1,
       const float* __restrict__ w2, u16* __restrict__ wf) {
  const int f = blockIdx.x * 256 + threadIdx.x;
  if (f >= 147456) return;
  const float* W; int local;
  if (f < 16384)      { W = w0; local = f; }
  else if (f < 81920) { W = w1; local = f - 16384; }
  else                { W = w2; local = f - 81920; }
  const int kc   = local >> 13;
  const int nt   = (local >> 9) & 15;
  const int lane = (local >> 3) & 63;
  const int j    = local & 7;
  const int k = kc*32 + (lane >> 4)*8 + j;
  const int n = nt*16 + (lane & 15);
  wf[f] = (u16)f2bf1(W[k*256 + n]);
}

extern "C" void kernel_launch(void* const* d_in, const int* in_sizes, int n_in,
                              void* d_out, int out_size, void* d_ws, size_t ws_size,
                              hipStream_t stream) {
  (void)n_in; (void)out_size; (void)ws_size;
  const float* xg   = (const float*)d_in[0];
  const float* w_in = (const float*)d_in[1];
  const float* b_in = (const float*)d_in[2];
  const float* w0   = (const float*)d_in[3];
  const float* as0  = (const float*)d_in[4];
  const float* ad0  = (const float*)d_in[5];
  const float* bi0  = (const float*)d_in[6];
  const float* w1   = (const float*)d_in[7];
  const float* as1  = (const float*)d_in[8];
  const float* ad1  = (const float*)d_in[9];
  const float* bi1  = (const float*)d_in[10];
  const float* w2   = (const float*)d_in[11];
  const float* as2  = (const float*)d_in[12];
  const float* ad2  = (const float*)d_in[13];
  const float* bi2  = (const float*)d_in[14];
  const float* mw1  = (const float*)d_in[15];
  const float* mb1  = (const float*)d_in[16];
  const float* g1   = (const float*)d_in[17];
  const float* be1  = (const float*)d_in[18];
  const float* mw2  = (const float*)d_in[19];
  const float* mb2  = (const float*)d_in[20];
  const float* g2   = (const float*)d_in[21];
  const float* be2  = (const float*)d_in[22];
  float* out = (float*)d_out;

  const int Btot = in_sizes[0] / 256;              // 8192
  u16* wf = (u16*)d_ws;                            // 147456 bf16 = 288 KB

  hipLaunchKernelGGL(prep_w, dim3(576), dim3(256), 0, stream, w0, w1, w2, wf);

  const int nblocks = (Btot + GPB - 1) / GPB;      // 1024
  hipLaunchKernelGGL(gat_main, dim3(nblocks), dim3(512), 0, stream,
                     xg, w_in, b_in, as0, ad0, bi0, as1, ad1, bi1,
                     as2, ad2, bi2, mw1, mb1, g1, be1, mw2, mb2, g2, be2,
                     wf, wf + 16384, wf + 81920, out, Btot);
}

// Round 3
// 185.347 us; speedup vs baseline: 6.4004x; 1.7534x over previous
//
#include <hip/hip_runtime.h>

typedef unsigned short u16;
typedef unsigned int   u32;
typedef __attribute__((ext_vector_type(8))) short bf16x8;
typedef __attribute__((ext_vector_type(4))) float f32x4;

#define GPB 4   // graphs per block; M = 64 rows

__constant__ int ADJ_DEG[16] = {3,4,4,3, 4,5,5,4, 4,5,5,4, 3,4,4,3};
__constant__ int ADJ_SRC[16][5] = {
  {0,1,4,0,0},   {1,0,2,5,0},   {2,1,3,6,0},   {3,2,7,0,0},
  {4,5,0,8,0},   {5,4,6,1,9},   {6,5,7,2,10},  {7,6,3,11,0},
  {8,9,4,12,0},  {9,8,10,5,13}, {10,9,11,6,14},{11,10,7,15,0},
  {12,13,8,0,0}, {13,12,14,9,0},{14,13,15,10,0},{15,14,11,0,0}
};

struct SMem {
  char hA[64*512];   // bf16 [64 rows][256 cols], XOR-swizzled (GEMM input / agg output)
  char hB[64*512];   // bf16 [64 rows][256 cols], XOR-swizzled (GEMM output x)
  union {
    struct { float h0f[64][17]; float w_in_s[16][64]; } pre;
    struct { float asd[64][4][2]; float ew[4][16][5][4]; } post;
  } u;
};  // 65536 + 8448 = 73984 B -> 2 blocks/CU

__device__ __forceinline__ int swz(int row, int b) { return (row << 9) + (b ^ ((row & 7) << 4)); }
__device__ __forceinline__ u32 f2bf1(float x) {           // RNE float->bf16 bits
  u32 u = __float_as_uint(x);
  return (u + 0x7fffu + ((u >> 16) & 1u)) >> 16;
}
__device__ __forceinline__ u32 pk(float a, float b) { return f2bf1(a) | (f2bf1(b) << 16); }
__device__ __forceinline__ float bflo(u32 u) { return __uint_as_float(u << 16); }
__device__ __forceinline__ float bfhi(u32 u) { return __uint_as_float(u & 0xffff0000u); }

// ---- GEMM x = hA @ W  (W frags from global/L2, no LDS staging, no barriers) ----
// swapped operands: mfma(Wfrag, Xfrag) -> lane holds out[row = tile+lane&15][cols = ct*16+(lane>>4)*4+reg]
// fused: attention dots a_s/a_d computed from fp32 acc, x written bf16-swizzled to hB
template<int KC>
__device__ __forceinline__ void gemm_att(SMem& sm, const u16* __restrict__ wfrag,
                                         const float* __restrict__ as_g,
                                         const float* __restrict__ ad_g, int t) {
  const int lane = t & 63;
  const int wc = (t >> 6) & 3;     // head / 64-col group
  const int wrh = t >> 8;          // row half (32 rows)
  const int l15 = lane & 15, lg = lane >> 4;
  const uint4* wsrc = (const uint4*)wfrag;

  f32x4 acc[4][2];
#pragma unroll
  for (int ct = 0; ct < 4; ++ct) {
    acc[ct][0] = (f32x4){0.f, 0.f, 0.f, 0.f};
    acc[ct][1] = (f32x4){0.f, 0.f, 0.f, 0.f};
  }

#pragma unroll
  for (int kc = 0; kc < KC; ++kc) {
    uint4 wfr[4];
#pragma unroll
    for (int ct = 0; ct < 4; ++ct)
      wfr[ct] = wsrc[(size_t)(((kc*16 + wc*4 + ct) << 6) + lane)];
    bf16x8 xfr[2];
#pragma unroll
    for (int rt = 0; rt < 2; ++rt)
      xfr[rt] = *(const bf16x8*)(sm.hA + swz(wrh*32 + rt*16 + l15, kc*64 + 16*lg));
#pragma unroll
    for (int ct = 0; ct < 4; ++ct) {
      bf16x8 wv = *(const bf16x8*)&wfr[ct];
#pragma unroll
      for (int rt = 0; rt < 2; ++rt)
        acc[ct][rt] = __builtin_amdgcn_mfma_f32_16x16x32_bf16(wv, xfr[rt], acc[ct][rt], 0, 0, 0);
    }
  }

  // fused attention dot products on fp32 accumulators
  float s1[2] = {0.f, 0.f}, s2[2] = {0.f, 0.f};
#pragma unroll
  for (int ct = 0; ct < 4; ++ct) {
    const float4 av = *(const float4*)(as_g + wc*64 + ct*16 + lg*4);
    const float4 dv = *(const float4*)(ad_g + wc*64 + ct*16 + lg*4);
#pragma unroll
    for (int rt = 0; rt < 2; ++rt) {
      const f32x4 a = acc[ct][rt];
      s1[rt] += a[0]*av.x + a[1]*av.y + a[2]*av.z + a[3]*av.w;
      s2[rt] += a[0]*dv.x + a[1]*dv.y + a[2]*dv.z + a[3]*dv.w;
    }
  }
#pragma unroll
  for (int rt = 0; rt < 2; ++rt) {
    s1[rt] += __shfl_xor(s1[rt], 16); s1[rt] += __shfl_xor(s1[rt], 32);
    s2[rt] += __shfl_xor(s2[rt], 16); s2[rt] += __shfl_xor(s2[rt], 32);
  }

  // x -> hB (bf16, swizzled), 8-byte writes (4 consecutive cols per lane)
#pragma unroll
  for (int ct = 0; ct < 4; ++ct)
#pragma unroll
    for (int rt = 0; rt < 2; ++rt) {
      uint2 o;
      o.x = pk(acc[ct][rt][0], acc[ct][rt][1]);
      o.y = pk(acc[ct][rt][2], acc[ct][rt][3]);
      *(uint2*)(sm.hB + swz(wrh*32 + rt*16 + l15, 2*(wc*64 + ct*16 + lg*4))) = o;
    }

  if (lg < 2) {   // one writer per (row, head)
    float2 v; v.x = s1[lg]; v.y = s2[lg];
    *(float2*)&sm.u.post.asd[wrh*32 + lg*16 + l15][wc][0] = v;
  }
}

__device__ __forceinline__ void softmax_edges(SMem& sm, int t) {
  if (t < 256) {
    const int g = t >> 6, d = (t >> 2) & 15, h = t & 3;
    const int deg = ADJ_DEG[d];
    const float advl = sm.u.post.asd[(g << 4) + d][h][1];
    float al[5]; float m = -1e30f;
#pragma unroll
    for (int k = 0; k < 5; ++k)
      if (k < deg) {
        float v = sm.u.post.asd[(g << 4) + ADJ_SRC[d][k]][h][0] + advl;
        v = (v > 0.f) ? v : 0.2f * v;          // leaky_relu 0.2
        al[k] = v; m = fmaxf(m, v);
      }
    float s = 0.f;
#pragma unroll
    for (int k = 0; k < 5; ++k)
      if (k < deg) { const float e = __expf(al[k] - m); al[k] = e; s += e; }
    const float inv = 1.f / s;
#pragma unroll
    for (int k = 0; k < 5; ++k)
      if (k < deg) sm.u.post.ew[g][d][k][h] = al[k] * inv;
  }
}

// thread (g, d, c2): one dst row, chunks ii*8+c2 (8 cols = 16B), head of chunk = ii
template<int MODE>   // 0: concat+bias+relu -> hA bf16; 1: mean heads + bias -> o64 fp32 (hA region)
__device__ __forceinline__ void aggregate(SMem& sm, const float* __restrict__ bias, int t) {
  const int g = t >> 7, d = (t >> 3) & 15, c2 = t & 7;
  const int deg = ADJ_DEG[d];
  const int drow = (g << 4) + d;
  float4 ewv[5]; int srow[5];
#pragma unroll
  for (int k = 0; k < 5; ++k) {
    float4 e = {0.f, 0.f, 0.f, 0.f};
    if (k < deg) e = *(const float4*)&sm.u.post.ew[g][d][k][0];
    ewv[k] = e;
    srow[k] = (g << 4) + ADJ_SRC[d][k];
  }
  float (*o64)[68] = (float (*)[68])sm.hA;
  float ms[8];
  if (MODE == 1) {
#pragma unroll
    for (int m = 0; m < 8; ++m) ms[m] = 0.f;
  }
#pragma unroll
  for (int ii = 0; ii < 4; ++ii) {
    const int byte0 = (ii*8 + c2) << 4;
    float a0=0.f,a1=0.f,a2=0.f,a3=0.f,a4=0.f,a5=0.f,a6=0.f,a7=0.f;
#pragma unroll
    for (int k = 0; k < 5; ++k) {
      const uint4 xv = *(const uint4*)(sm.hB + swz(srow[k], byte0));
      const float wk = (ii == 0) ? ewv[k].x : (ii == 1) ? ewv[k].y : (ii == 2) ? ewv[k].z : ewv[k].w;
      a0 = fmaf(wk, bflo(xv.x), a0); a1 = fmaf(wk, bfhi(xv.x), a1);
      a2 = fmaf(wk, bflo(xv.y), a2); a3 = fmaf(wk, bfhi(xv.y), a3);
      a4 = fmaf(wk, bflo(xv.z), a4); a5 = fmaf(wk, bfhi(xv.z), a5);
      a6 = fmaf(wk, bflo(xv.w), a6); a7 = fmaf(wk, bfhi(xv.w), a7);
    }
    if (MODE == 0) {
      const int col0 = ii*64 + c2*8;
      const float4 b0 = *(const float4*)(bias + col0);
      const float4 b1 = *(const float4*)(bias + col0 + 4);
      uint4 uo;
      uo.x = pk(fmaxf(a0 + b0.x, 0.f), fmaxf(a1 + b0.y, 0.f));
      uo.y = pk(fmaxf(a2 + b0.z, 0.f), fmaxf(a3 + b0.w, 0.f));
      uo.z = pk(fmaxf(a4 + b1.x, 0.f), fmaxf(a5 + b1.y, 0.f));
      uo.w = pk(fmaxf(a6 + b1.z, 0.f), fmaxf(a7 + b1.w, 0.f));
      *(uint4*)(sm.hA + swz(drow, byte0)) = uo;
    } else {
      ms[0]+=a0; ms[1]+=a1; ms[2]+=a2; ms[3]+=a3;
      ms[4]+=a4; ms[5]+=a5; ms[6]+=a6; ms[7]+=a7;
    }
  }
  if (MODE == 1) {
    const int col0 = c2*8;
#pragma unroll
    for (int m = 0; m < 8; ++m)
      o64[drow][col0 + m] = fmaf(0.25f, ms[m], bias[col0 + m]);
  }
}

extern "C" __global__ void __launch_bounds__(512, 4)
gat_main(const float* __restrict__ xg,
         const float* __restrict__ w_in, const float* __restrict__ b_in,
         const float* __restrict__ as0, const float* __restrict__ ad0, const float* __restrict__ bias0,
         const float* __restrict__ as1, const float* __restrict__ ad1, const float* __restrict__ bias1,
         const float* __restrict__ as2, const float* __restrict__ ad2, const float* __restrict__ bias2,
         const u16* __restrict__ wf0, const u16* __restrict__ wf1, const u16* __restrict__ wf2,
         float* __restrict__ gr, int Btot)
{
  __shared__ SMem sm;
  const int t = threadIdx.x;
  const int b0 = blockIdx.x * GPB;
  if (b0 >= Btot) return;

  // ---- load x (transpose to node-major) + stage w_in ----
  if (t < 256) {
    const float4 v = *(const float4*)(xg + (size_t)b0*256 + 4*t);
    const int flat = 4*t, g = flat >> 8, rem = flat & 255;
    const int c = rem >> 4, n0 = rem & 15;
    sm.u.pre.h0f[(g << 4) + n0 + 0][c] = v.x;
    sm.u.pre.h0f[(g << 4) + n0 + 1][c] = v.y;
    sm.u.pre.h0f[(g << 4) + n0 + 2][c] = v.z;
    sm.u.pre.h0f[(g << 4) + n0 + 3][c] = v.w;
    ((float4*)sm.u.pre.w_in_s)[t] = ((const float4*)w_in)[t];
  }
  __syncthreads();

  // ---- in-proj: h1 = relu(h0 @ w_in + b_in) -> hA bf16 swizzled (64 cols) ----
  {
    const int r = t >> 3, q = t & 7;
    const float4 bA = *(const float4*)(b_in + 8*q);
    const float4 bB = *(const float4*)(b_in + 8*q + 4);
    float a0=bA.x,a1=bA.y,a2=bA.z,a3=bA.w,a4=bB.x,a5=bB.y,a6=bB.z,a7=bB.w;
#pragma unroll
    for (int k = 0; k < 16; ++k) {
      const float hv = sm.u.pre.h0f[r][k];
      const float4 wA = *(const float4*)(&sm.u.pre.w_in_s[k][8*q]);
      const float4 wB = *(const float4*)(&sm.u.pre.w_in_s[k][8*q + 4]);
      a0 = fmaf(hv, wA.x, a0); a1 = fmaf(hv, wA.y, a1);
      a2 = fmaf(hv, wA.z, a2); a3 = fmaf(hv, wA.w, a3);
      a4 = fmaf(hv, wB.x, a4); a5 = fmaf(hv, wB.y, a5);
      a6 = fmaf(hv, wB.z, a6); a7 = fmaf(hv, wB.w, a7);
    }
    uint4 uo;
    uo.x = pk(fmaxf(a0,0.f), fmaxf(a1,0.f));
    uo.y = pk(fmaxf(a2,0.f), fmaxf(a3,0.f));
    uo.z = pk(fmaxf(a4,0.f), fmaxf(a5,0.f));
    uo.w = pk(fmaxf(a6,0.f), fmaxf(a7,0.f));
    *(uint4*)(sm.hA + swz(r, 16*q)) = uo;
  }
  __syncthreads();

  // ---- GAT layer 0 (K=64) ----
  gemm_att<2>(sm, wf0, as0, ad0, t); __syncthreads();
  softmax_edges(sm, t);              __syncthreads();
  aggregate<0>(sm, bias0, t);        __syncthreads();

  // ---- GAT layer 1 (K=256) ----
  gemm_att<8>(sm, wf1, as1, ad1, t); __syncthreads();
  softmax_edges(sm, t);              __syncthreads();
  aggregate<0>(sm, bias1, t);        __syncthreads();

  // ---- GAT layer 2 (K=256, mean over heads) ----
  gemm_att<8>(sm, wf2, as2, ad2, t); __syncthreads();
  softmax_edges(sm, t);              __syncthreads();
  aggregate<1>(sm, bias2, t);        __syncthreads();

  // ---- global mean pool over 16 nodes -> gr ----
  if (t < 256) {
    const int g = t >> 6, col = t & 63;
    float (*o64)[68] = (float (*)[68])sm.hA;
    float s = 0.f;
#pragma unroll
    for (int r = 0; r < 16; ++r) s += o64[(g << 4) + r][col];
    gr[(size_t)(b0 + g)*64 + col] = s * (1.f/16.f);
  }
}

// ---- MLP kernel: weights staged in LDS once per block, 32 graphs/block ----
struct MlpS {
  float mw1s[64][128];   // 32 KB fp32
  u32   mw2s[128][128];  // 64 KB bf16-pairs
  float grs[4][64];
  float z1[4][128];
  float red1[8][2];
  float red2[8][2];
};

extern "C" __global__ void __launch_bounds__(512, 2)
mlp_kernel(const float* __restrict__ mw1, const float* __restrict__ mb1,
           const float* __restrict__ g1, const float* __restrict__ be1,
           const u16* __restrict__ mwb2, const float* __restrict__ mb2,
           const float* __restrict__ g2, const float* __restrict__ be2,
           const float* __restrict__ gr, float* __restrict__ out, int Btot)
{
  __shared__ MlpS sm;
  const int t = threadIdx.x;
#pragma unroll
  for (int i = 0; i < 4; ++i)
    ((float4*)sm.mw1s)[t + 512*i] = ((const float4*)mw1)[t + 512*i];
#pragma unroll
  for (int i = 0; i < 8; ++i)
    ((uint4*)sm.mw2s)[t + 512*i] = ((const uint4*)mwb2)[t + 512*i];

  const int g = t >> 7, o = t & 127, w = t >> 6, lane = t & 63;
  const float bb1 = mb1[o], gg1 = g1[o], bbe1 = be1[o];
  const float2 bb2  = *(const float2*)(mb2 + 2*o);
  const float2 gg2  = *(const float2*)(g2  + 2*o);
  const float2 bbe2 = *(const float2*)(be2 + 2*o);

  const int iters = (Btot + 1023) / 1024;
  for (int it = 0; it < iters; ++it) {
    const int base = blockIdx.x*4 + it*1024;
    __syncthreads();
    if (t < 256 && base + (t >> 6) < Btot)
      sm.grs[t >> 6][t & 63] = gr[(size_t)(base + (t >> 6))*64 + (t & 63)];
    __syncthreads();
    if (base + g >= Btot) continue;

    // MLP1 [64]->[128]
    float a = bb1;
#pragma unroll
    for (int k = 0; k < 64; ++k) a = fmaf(sm.grs[g][k], sm.mw1s[k][o], a);
    float su = a, sq = a*a;
#pragma unroll
    for (int off = 32; off >= 1; off >>= 1) { su += __shfl_xor(su, off); sq += __shfl_xor(sq, off); }
    if (lane == 0) { sm.red1[w][0] = su; sm.red1[w][1] = sq; }
    __syncthreads();
    {
      const float mu = (sm.red1[2*g][0] + sm.red1[2*g+1][0]) * (1.f/128.f);
      const float mq = (sm.red1[2*g][1] + sm.red1[2*g+1][1]) * (1.f/128.f);
      const float rstd = rsqrtf(mq - mu*mu + 1e-5f);
      sm.z1[g][o] = fmaxf((a - mu)*rstd*gg1 + bbe1, 0.f);
    }
    __syncthreads();

    // MLP2 [128]->[256]
    float c0 = bb2.x, c1 = bb2.y;
#pragma unroll
    for (int k = 0; k < 128; ++k) {
      const float zk = sm.z1[g][k];
      const u32 u = sm.mw2s[k][o];
      c0 = fmaf(zk, bflo(u), c0);
      c1 = fmaf(zk, bfhi(u), c1);
    }
    float su2 = c0 + c1, sq2 = c0*c0 + c1*c1;
#pragma unroll
    for (int off = 32; off >= 1; off >>= 1) { su2 += __shfl_xor(su2, off); sq2 += __shfl_xor(sq2, off); }
    if (lane == 0) { sm.red2[w][0] = su2; sm.red2[w][1] = sq2; }
    __syncthreads();
    {
      const float mu = (sm.red2[2*g][0] + sm.red2[2*g+1][0]) * (1.f/256.f);
      const float mq = (sm.red2[2*g][1] + sm.red2[2*g+1][1]) * (1.f/256.f);
      const float rstd = rsqrtf(mq - mu*mu + 1e-5f);
      float2 ov;
      ov.x = fmaxf((c0 - mu)*rstd*gg2.x + bbe2.x, 0.f);
      ov.y = fmaxf((c1 - mu)*rstd*gg2.y + bbe2.y, 0.f);
      *(float2*)(out + (size_t)(base + g)*256 + 2*o) = ov;
    }
  }
}

// ---- prepass: W0/W1/W2 -> bf16 MFMA fragment layout; mw2 -> bf16 row-major ----
__global__ void __launch_bounds__(256)
prep_w(const float* __restrict__ w0, const float* __restrict__ w1,
       const float* __restrict__ w2, const float* __restrict__ mw2,
       u16* __restrict__ wf) {
  const int f = blockIdx.x*256 + threadIdx.x;
  if (f >= 180224) return;
  if (f >= 147456) { wf[f] = (u16)f2bf1(mw2[f - 147456]); return; }
  const float* W; int local;
  if (f < 16384)      { W = w0; local = f; }
  else if (f < 81920) { W = w1; local = f - 16384; }
  else                { W = w2; local = f - 81920; }
  const int kc = local >> 13, nt = (local >> 9) & 15, lane = (local >> 3) & 63, j = local & 7;
  wf[f] = (u16)f2bf1(W[(kc*32 + (lane >> 4)*8 + j)*256 + nt*16 + (lane & 15)]);
}

extern "C" void kernel_launch(void* const* d_in, const int* in_sizes, int n_in,
                              void* d_out, int out_size, void* d_ws, size_t ws_size,
                              hipStream_t stream) {
  (void)n_in; (void)out_size; (void)ws_size;
  const float* xg   = (const float*)d_in[0];
  const float* w_in = (const float*)d_in[1];
  const float* b_in = (const float*)d_in[2];
  const float* w0   = (const float*)d_in[3];
  const float* as0  = (const float*)d_in[4];
  const float* ad0  = (const float*)d_in[5];
  const float* bi0  = (const float*)d_in[6];
  const float* w1   = (const float*)d_in[7];
  const float* as1  = (const float*)d_in[8];
  const float* ad1  = (const float*)d_in[9];
  const float* bi1  = (const float*)d_in[10];
  const float* w2   = (const float*)d_in[11];
  const float* as2  = (const float*)d_in[12];
  const float* ad2  = (const float*)d_in[13];
  const float* bi2  = (const float*)d_in[14];
  const float* mw1  = (const float*)d_in[15];
  const float* mb1  = (const float*)d_in[16];
  const float* g1   = (const float*)d_in[17];
  const float* be1  = (const float*)d_in[18];
  const float* mw2  = (const float*)d_in[19];
  const float* mb2  = (const float*)d_in[20];
  const float* g2   = (const float*)d_in[21];
  const float* be2  = (const float*)d_in[22];
  float* out = (float*)d_out;

  const int Btot = in_sizes[0] / 256;               // 8192
  u16* wf = (u16*)d_ws;                             // 180224 bf16 = 352 KB
  const u16* mwb2 = wf + 147456;
  float* gr = (float*)((char*)d_ws + 360448);       // [Btot][64] fp32

  hipLaunchKernelGGL(prep_w, dim3(704), dim3(256), 0, stream, w0, w1, w2, mw2, wf);

  const int nblocks = (Btot + GPB - 1) / GPB;       // 2048
  hipLaunchKernelGGL(gat_main, dim3(nblocks), dim3(512), 0, stream,
                     xg, w_in, b_in, as0, ad0, bi0, as1, ad1, bi1,
                     as2, ad2, bi2, wf, wf + 16384, wf + 81920, gr, Btot);

  hipLaunchKernelGGL(mlp_kernel, dim3(256), dim3(512), 0, stream,
                     mw1, mb1, g1, be1, mwb2, mb2, g2, be2, gr, out, Btot);
}

// Round 4
// 174.127 us; speedup vs baseline: 6.8128x; 1.0644x over previous
//
#include <hip/hip_runtime.h>

typedef unsigned short u16;
typedef unsigned int   u32;
typedef __attribute__((ext_vector_type(8))) short bf16x8;
typedef __attribute__((ext_vector_type(4))) float f32x4;

#define GPB 4   // graphs per block; M = 64 rows

__constant__ int ADJ_DEG[16] = {3,4,4,3, 4,5,5,4, 4,5,5,4, 3,4,4,3};
__constant__ int ADJ_SRC[16][5] = {
  {0,1,4,0,0},   {1,0,2,5,0},   {2,1,3,6,0},   {3,2,7,0,0},
  {4,5,0,8,0},   {5,4,6,1,9},   {6,5,7,2,10},  {7,6,3,11,0},
  {8,9,4,12,0},  {9,8,10,5,13}, {10,9,11,6,14},{11,10,7,15,0},
  {12,13,8,0,0}, {13,12,14,9,0},{14,13,15,10,0},{15,14,11,0,0}
};

struct SMem {
  char hA[64*512];      // bf16 [64 rows][256 cols], XOR-swizzled (GEMM A / agg output / o64 fp32)
  char hBT[4*256*32];   // bf16 X^T: [g][c 0..255][s 0..15], 32B rows (agg A-operand)
  union {
    struct { float h0f[64][17]; float w_in_s[16][64]; } pre;            // 8448
    struct { float asd[64][4][2]; char ptb[8192]; } post;               // 2048 + PT frags (16 (g,h) x 32 lanes x 16B)
    struct { float grs[4][64]; float z1[4][128]; float red[2][8][2]; } mlp;
  } u;
};  // 32768 + 32768 + 10240 = 75776 B -> 2 blocks/CU

__device__ __forceinline__ int swz(int row, int b) { return (row << 9) + (b ^ ((row & 7) << 4)); }
__device__ __forceinline__ u32 f2bf1(float x) {           // RNE float->bf16 bits
  u32 u = __float_as_uint(x);
  return (u + 0x7fffu + ((u >> 16) & 1u)) >> 16;
}
__device__ __forceinline__ u32 pk(float a, float b) { return f2bf1(a) | (f2bf1(b) << 16); }
__device__ __forceinline__ float bflo(u32 u) { return __uint_as_float(u << 16); }
__device__ __forceinline__ float bfhi(u32 u) { return __uint_as_float(u & 0xffff0000u); }

// ---- GEMM x = hA @ W (W frags from L2, no barriers), fused attention dots.
// mfma(W_as_A, X_as_B): lane holds out[node r = l15][cols c0..c0+3].
// Epilogue writes X^T to hBT[g][c][s] (bf16).
template<int KC>
__device__ __forceinline__ void gemm_att(SMem& sm, const u16* __restrict__ wfrag,
                                         const float* __restrict__ as_g,
                                         const float* __restrict__ ad_g, int t) {
  const int lane = t & 63;
  const int wc = (t >> 6) & 3;     // head / 64-col group
  const int wrh = t >> 8;          // row half (32 rows)
  const int l15 = lane & 15, lg = lane >> 4;
  const uint4* wsrc = (const uint4*)wfrag;

  f32x4 acc[4][2];
#pragma unroll
  for (int ct = 0; ct < 4; ++ct) {
    acc[ct][0] = (f32x4){0.f, 0.f, 0.f, 0.f};
    acc[ct][1] = (f32x4){0.f, 0.f, 0.f, 0.f};
  }

#pragma unroll
  for (int kc = 0; kc < KC; ++kc) {
    uint4 wfr[4];
#pragma unroll
    for (int ct = 0; ct < 4; ++ct)
      wfr[ct] = wsrc[(size_t)(((kc*16 + wc*4 + ct) << 6) + lane)];
    bf16x8 xfr[2];
#pragma unroll
    for (int rt = 0; rt < 2; ++rt)
      xfr[rt] = *(const bf16x8*)(sm.hA + swz(wrh*32 + rt*16 + l15, kc*64 + 16*lg));
#pragma unroll
    for (int ct = 0; ct < 4; ++ct) {
      bf16x8 wv = *(const bf16x8*)&wfr[ct];
#pragma unroll
      for (int rt = 0; rt < 2; ++rt)
        acc[ct][rt] = __builtin_amdgcn_mfma_f32_16x16x32_bf16(wv, xfr[rt], acc[ct][rt], 0, 0, 0);
    }
  }

  // fused attention dot products on fp32 accumulators
  float s1[2] = {0.f, 0.f}, s2[2] = {0.f, 0.f};
#pragma unroll
  for (int ct = 0; ct < 4; ++ct) {
    const float4 av = *(const float4*)(as_g + wc*64 + ct*16 + lg*4);
    const float4 dv = *(const float4*)(ad_g + wc*64 + ct*16 + lg*4);
#pragma unroll
    for (int rt = 0; rt < 2; ++rt) {
      const f32x4 a = acc[ct][rt];
      s1[rt] += a[0]*av.x + a[1]*av.y + a[2]*av.z + a[3]*av.w;
      s2[rt] += a[0]*dv.x + a[1]*dv.y + a[2]*dv.z + a[3]*dv.w;
    }
  }
#pragma unroll
  for (int rt = 0; rt < 2; ++rt) {
    s1[rt] += __shfl_xor(s1[rt], 16); s1[rt] += __shfl_xor(s1[rt], 32);
    s2[rt] += __shfl_xor(s2[rt], 16); s2[rt] += __shfl_xor(s2[rt], 32);
  }

  // epilogue: X^T -> hBT[g][c][s]
#pragma unroll
  for (int ct = 0; ct < 4; ++ct) {
    const int c0 = wc*64 + ct*16 + lg*4;
#pragma unroll
    for (int rt = 0; rt < 2; ++rt) {
      const int r = wrh*32 + rt*16 + l15;
      char* dst = sm.hBT + ((r >> 4) << 13) + ((r & 15) << 1);
#pragma unroll
      for (int i = 0; i < 4; ++i)
        *(u16*)(dst + (c0 + i)*32) = (u16)f2bf1(acc[ct][rt][i]);
    }
  }

  if (lg < 2) {   // one writer per (row, head); lg selects rt
    float2 v; v.x = s1[lg]; v.y = s2[lg];
    *(float2*)&sm.u.post.asd[wrh*32 + lg*16 + l15][wc][0] = v;
  }
}

// ---- softmax over incoming edges; scatter into P^T B-fragments (bf16, K=32 zero-padded) ----
__device__ __forceinline__ void softmax_pt(SMem& sm, int t) {
  if (t < 256) {
    const int g = t >> 6, d = (t >> 2) & 15, h = t & 3;
    const int deg = ADJ_DEG[d];
    const float advl = sm.u.post.asd[(g << 4) + d][h][1];
    float al[5]; int srcs[5];
    float m = -1e30f;
#pragma unroll
    for (int k = 0; k < 5; ++k) {
      srcs[k] = (k < deg) ? ADJ_SRC[d][k] : 99;
      float v = 0.f;
      if (k < deg) {
        v = sm.u.post.asd[(g << 4) + ADJ_SRC[d][k]][h][0] + advl;
        v = (v > 0.f) ? v : 0.2f * v;          // leaky_relu 0.2
        m = fmaxf(m, v);
      }
      al[k] = v;
    }
    float ssum = 0.f;
#pragma unroll
    for (int k = 0; k < 5; ++k)
      if (k < deg) { const float e = __expf(al[k] - m); al[k] = e; ssum += e; }
    const float inv = 1.f / ssum;
    // dense P row (compile-time indices; runtime srcs via compare-select)
    float p[16];
#pragma unroll
    for (int s = 0; s < 16; ++s) {
      float v = 0.f;
#pragma unroll
      for (int k = 0; k < 5; ++k) v = (srcs[k] == s) ? al[k] * inv : v;
      p[s] = v;
    }
    uint4 lo, hi;
    lo.x = pk(p[0],p[1]);   lo.y = pk(p[2],p[3]);   lo.z = pk(p[4],p[5]);   lo.w = pk(p[6],p[7]);
    hi.x = pk(p[8],p[9]);   hi.y = pk(p[10],p[11]); hi.z = pk(p[12],p[13]); hi.w = pk(p[14],p[15]);
    // B-frag: lane = lg*16 + d holds B[k=lg*8+j][n=d] = P[d][lg*8+j]; lanes>=32 are zero (k>=16)
    char* pt = sm.u.post.ptb + (((g*4 + h)*32 + d) << 4);
    *(uint4*)pt = lo;
    *(uint4*)(pt + 256) = hi;
  }
}

// ---- aggregation via MFMA: agg^T = X^T @ P^T; D: lane holds [c = ctile*16+lg*4+reg][d = l15] ----
template<int MODE>   // 0: concat+bias+relu -> hA bf16; 1: mean heads + bias -> o64 fp32 (hA region)
__device__ __forceinline__ void aggregate_mfma(SMem& sm, const float* __restrict__ bias, int t) {
  const int lane = t & 63, w = t >> 6;
  const int g = w >> 1, l15 = lane & 15, lg = lane >> 4;
  const bf16x8 zero8 = {0,0,0,0,0,0,0,0};

  if (MODE == 0) {
#pragma unroll
    for (int hp = 0; hp < 2; ++hp) {
      const int h = (w & 1)*2 + hp;
      bf16x8 b = zero8;
      if (lane < 32) b = *(const bf16x8*)(sm.u.post.ptb + (((g*4 + h)*32 + lane) << 4));
#pragma unroll
      for (int ctile = 0; ctile < 4; ++ctile) {
        bf16x8 a = zero8;
        if (lane < 32) {
          const int c_row = h*64 + ctile*16 + l15;
          a = *(const bf16x8*)(sm.hBT + (g << 13) + c_row*32 + lg*16);
        }
        f32x4 acc = {0.f, 0.f, 0.f, 0.f};
        acc = __builtin_amdgcn_mfma_f32_16x16x32_bf16(a, b, acc, 0, 0, 0);
        const int c0 = h*64 + ctile*16 + lg*4;
        const float4 bv = *(const float4*)(bias + c0);
        uint2 o;
        o.x = pk(fmaxf(acc[0] + bv.x, 0.f), fmaxf(acc[1] + bv.y, 0.f));
        o.y = pk(fmaxf(acc[2] + bv.z, 0.f), fmaxf(acc[3] + bv.w, 0.f));
        *(uint2*)(sm.hA + swz(g*16 + l15, 2*c0)) = o;
      }
    }
  } else {
    const int half = w & 1;
    float (*o64)[68] = (float (*)[68])sm.hA;
#pragma unroll
    for (int ct2 = 0; ct2 < 2; ++ct2) {
      f32x4 acc = {0.f, 0.f, 0.f, 0.f};
#pragma unroll
      for (int h = 0; h < 4; ++h) {          // chain heads into one accumulator (sum over heads)
        bf16x8 a = zero8, b = zero8;
        if (lane < 32) {
          b = *(const bf16x8*)(sm.u.post.ptb + (((g*4 + h)*32 + lane) << 4));
          const int c_row = h*64 + half*32 + ct2*16 + l15;
          a = *(const bf16x8*)(sm.hBT + (g << 13) + c_row*32 + lg*16);
        }
        acc = __builtin_amdgcn_mfma_f32_16x16x32_bf16(a, b, acc, 0, 0, 0);
      }
      const int ci = half*32 + ct2*16 + lg*4;
      const float4 bv = *(const float4*)(bias + ci);
      float4 ov;
      ov.x = fmaf(0.25f, acc[0], bv.x);
      ov.y = fmaf(0.25f, acc[1], bv.y);
      ov.z = fmaf(0.25f, acc[2], bv.z);
      ov.w = fmaf(0.25f, acc[3], bv.w);
      *(float4*)&o64[(g << 4) + l15][ci] = ov;
    }
  }
}

extern "C" __global__ void __launch_bounds__(512, 4)
gat_main(const float* __restrict__ xg,
         const float* __restrict__ w_in, const float* __restrict__ b_in,
         const float* __restrict__ as0, const float* __restrict__ ad0, const float* __restrict__ bias0,
         const float* __restrict__ as1, const float* __restrict__ ad1, const float* __restrict__ bias1,
         const float* __restrict__ as2, const float* __restrict__ ad2, const float* __restrict__ bias2,
         const u16* __restrict__ wf0, const u16* __restrict__ wf1, const u16* __restrict__ wf2,
         const float* __restrict__ mw1, const float* __restrict__ mb1,
         const float* __restrict__ g1, const float* __restrict__ be1,
         const u32* __restrict__ mwb2, const float* __restrict__ mb2,
         const float* __restrict__ g2, const float* __restrict__ be2,
         float* __restrict__ out, int Btot)
{
  __shared__ SMem sm;
  const int t = threadIdx.x;
  const int b0 = blockIdx.x * GPB;
  if (b0 >= Btot) return;

  // ---- load x (transpose to node-major) + stage w_in ----
  if (t < 256) {
    const float4 v = *(const float4*)(xg + (size_t)b0*256 + 4*t);
    const int flat = 4*t, g = flat >> 8, rem = flat & 255;
    const int c = rem >> 4, n0 = rem & 15;
    sm.u.pre.h0f[(g << 4) + n0 + 0][c] = v.x;
    sm.u.pre.h0f[(g << 4) + n0 + 1][c] = v.y;
    sm.u.pre.h0f[(g << 4) + n0 + 2][c] = v.z;
    sm.u.pre.h0f[(g << 4) + n0 + 3][c] = v.w;
    ((float4*)sm.u.pre.w_in_s)[t] = ((const float4*)w_in)[t];
  }
  __syncthreads();

  // ---- in-proj: h1 = relu(h0 @ w_in + b_in) -> hA bf16 swizzled (64 cols) ----
  {
    const int r = t >> 3, q = t & 7;
    const float4 bA = *(const float4*)(b_in + 8*q);
    const float4 bB = *(const float4*)(b_in + 8*q + 4);
    float a0=bA.x,a1=bA.y,a2=bA.z,a3=bA.w,a4=bB.x,a5=bB.y,a6=bB.z,a7=bB.w;
#pragma unroll
    for (int k = 0; k < 16; ++k) {
      const float hv = sm.u.pre.h0f[r][k];
      const float4 wA = *(const float4*)(&sm.u.pre.w_in_s[k][8*q]);
      const float4 wB = *(const float4*)(&sm.u.pre.w_in_s[k][8*q + 4]);
      a0 = fmaf(hv, wA.x, a0); a1 = fmaf(hv, wA.y, a1);
      a2 = fmaf(hv, wA.z, a2); a3 = fmaf(hv, wA.w, a3);
      a4 = fmaf(hv, wB.x, a4); a5 = fmaf(hv, wB.y, a5);
      a6 = fmaf(hv, wB.z, a6); a7 = fmaf(hv, wB.w, a7);
    }
    uint4 uo;
    uo.x = pk(fmaxf(a0,0.f), fmaxf(a1,0.f));
    uo.y = pk(fmaxf(a2,0.f), fmaxf(a3,0.f));
    uo.z = pk(fmaxf(a4,0.f), fmaxf(a5,0.f));
    uo.w = pk(fmaxf(a6,0.f), fmaxf(a7,0.f));
    *(uint4*)(sm.hA + swz(r, 16*q)) = uo;
  }
  __syncthreads();

  // ---- GAT layer 0 (K=64) ----
  gemm_att<2>(sm, wf0, as0, ad0, t);  __syncthreads();
  softmax_pt(sm, t);                  __syncthreads();
  aggregate_mfma<0>(sm, bias0, t);    __syncthreads();

  // ---- GAT layer 1 (K=256) ----
  gemm_att<8>(sm, wf1, as1, ad1, t);  __syncthreads();
  softmax_pt(sm, t);                  __syncthreads();
  aggregate_mfma<0>(sm, bias1, t);    __syncthreads();

  // ---- GAT layer 2 (K=256, mean over heads) ----
  gemm_att<8>(sm, wf2, as2, ad2, t);  __syncthreads();
  softmax_pt(sm, t);                  __syncthreads();
  aggregate_mfma<1>(sm, bias2, t);    __syncthreads();

  // ---- global mean pool over 16 nodes ----
  if (t < 256) {
    const int g = t >> 6, col = t & 63;
    const float (*o64)[68] = (const float (*)[68])sm.hA;
    float s = 0.f;
#pragma unroll
    for (int r = 0; r < 16; ++r) s += o64[(g << 4) + r][col];
    sm.u.mlp.grs[g][col] = s * (1.f/16.f);
  }
  __syncthreads();

  // ---- fused MLP (weights from L2) ----
  const int mg = t >> 7, o = t & 127, w = t >> 6, lane = t & 63;
  // MLP1 [64]->[128]
  float a = mb1[o];
#pragma unroll 8
  for (int k = 0; k < 64; ++k) a = fmaf(sm.u.mlp.grs[mg][k], mw1[k*128 + o], a);
  float su = a, sq = a*a;
#pragma unroll
  for (int off = 32; off >= 1; off >>= 1) { su += __shfl_xor(su, off); sq += __shfl_xor(sq, off); }
  if (lane == 0) { sm.u.mlp.red[0][w][0] = su; sm.u.mlp.red[0][w][1] = sq; }
  __syncthreads();
  {
    const float mu = (sm.u.mlp.red[0][2*mg][0] + sm.u.mlp.red[0][2*mg+1][0]) * (1.f/128.f);
    const float mq = (sm.u.mlp.red[0][2*mg][1] + sm.u.mlp.red[0][2*mg+1][1]) * (1.f/128.f);
    const float rstd = rsqrtf(mq - mu*mu + 1e-5f);
    sm.u.mlp.z1[mg][o] = fmaxf((a - mu)*rstd*g1[o] + be1[o], 0.f);
  }
  __syncthreads();
  // MLP2 [128]->[256], LN, relu, store
  {
    const float2 bb2 = *(const float2*)(mb2 + 2*o);
    float c0 = bb2.x, c1 = bb2.y;
#pragma unroll 8
    for (int k = 0; k < 128; ++k) {
      const float zk = sm.u.mlp.z1[mg][k];
      const u32 uw = mwb2[k*128 + o];
      c0 = fmaf(zk, bflo(uw), c0);
      c1 = fmaf(zk, bfhi(uw), c1);
    }
    float su2 = c0 + c1, sq2 = c0*c0 + c1*c1;
#pragma unroll
    for (int off = 32; off >= 1; off >>= 1) { su2 += __shfl_xor(su2, off); sq2 += __shfl_xor(sq2, off); }
    if (lane == 0) { sm.u.mlp.red[1][w][0] = su2; sm.u.mlp.red[1][w][1] = sq2; }
    __syncthreads();
    const float mu = (sm.u.mlp.red[1][2*mg][0] + sm.u.mlp.red[1][2*mg+1][0]) * (1.f/256.f);
    const float mq = (sm.u.mlp.red[1][2*mg][1] + sm.u.mlp.red[1][2*mg+1][1]) * (1.f/256.f);
    const float rstd = rsqrtf(mq - mu*mu + 1e-5f);
    const float2 gg2  = *(const float2*)(g2  + 2*o);
    const float2 bbe2 = *(const float2*)(be2 + 2*o);
    float2 ov;
    ov.x = fmaxf((c0 - mu)*rstd*gg2.x + bbe2.x, 0.f);
    ov.y = fmaxf((c1 - mu)*rstd*gg2.y + bbe2.y, 0.f);
    *(float2*)(out + (size_t)(b0 + mg)*256 + 2*o) = ov;
  }
}

// ---- prepass: W0/W1/W2 -> bf16 MFMA fragment layout; mw2 -> bf16 row-major ----
__global__ void __launch_bounds__(256)
prep_w(const float* __restrict__ w0, const float* __restrict__ w1,
       const float* __restrict__ w2, const float* __restrict__ mw2,
       u16* __restrict__ wf) {
  const int f = blockIdx.x*256 + threadIdx.x;
  if (f >= 180224) return;
  if (f >= 147456) { wf[f] = (u16)f2bf1(mw2[f - 147456]); return; }
  const float* W; int local;
  if (f < 16384)      { W = w0; local = f; }
  else if (f < 81920) { W = w1; local = f - 16384; }
  else                { W = w2; local = f - 81920; }
  const int kc = local >> 13, nt = (local >> 9) & 15, lane = (local >> 3) & 63, j = local & 7;
  wf[f] = (u16)f2bf1(W[(kc*32 + (lane >> 4)*8 + j)*256 + nt*16 + (lane & 15)]);
}

extern "C" void kernel_launch(void* const* d_in, const int* in_sizes, int n_in,
                              void* d_out, int out_size, void* d_ws, size_t ws_size,
                              hipStream_t stream) {
  (void)n_in; (void)out_size; (void)ws_size;
  const float* xg   = (const float*)d_in[0];
  const float* w_in = (const float*)d_in[1];
  const float* b_in = (const float*)d_in[2];
  const float* w0   = (const float*)d_in[3];
  const float* as0  = (const float*)d_in[4];
  const float* ad0  = (const float*)d_in[5];
  const float* bi0  = (const float*)d_in[6];
  const float* w1   = (const float*)d_in[7];
  const float* as1  = (const float*)d_in[8];
  const float* ad1  = (const float*)d_in[9];
  const float* bi1  = (const float*)d_in[10];
  const float* w2   = (const float*)d_in[11];
  const float* as2  = (const float*)d_in[12];
  const float* ad2  = (const float*)d_in[13];
  const float* bi2  = (const float*)d_in[14];
  const float* mw1  = (const float*)d_in[15];
  const float* mb1  = (const float*)d_in[16];
  const float* g1   = (const float*)d_in[17];
  const float* be1  = (const float*)d_in[18];
  const float* mw2  = (const float*)d_in[19];
  const float* mb2  = (const float*)d_in[20];
  const float* g2   = (const float*)d_in[21];
  const float* be2  = (const float*)d_in[22];
  float* out = (float*)d_out;

  const int Btot = in_sizes[0] / 256;               // 8192
  u16* wf = (u16*)d_ws;                             // 180224 bf16 = 352 KB
  const u32* mwb2 = (const u32*)(wf + 147456);

  hipLaunchKernelGGL(prep_w, dim3(704), dim3(256), 0, stream, w0, w1, w2, mw2, wf);

  const int nblocks = (Btot + GPB - 1) / GPB;       // 2048
  hipLaunchKernelGGL(gat_main, dim3(nblocks), dim3(512), 0, stream,
                     xg, w_in, b_in, as0, ad0, bi0, as1, ad1, bi1,
                     as2, ad2, bi2, wf, wf + 16384, wf + 81920,
                     mw1, mb1, g1, be1, mwb2, mb2, g2, be2, out, Btot);
}